// Round 3
// baseline (229.997 us; speedup 1.0000x reference)
//
#include <hip/hip_runtime.h>

// Problem constants (N,C,H,W) = (8,19,384,384)
#define NCLS 19
#define HW   147456            // 384*384
#define MPIX 1179648           // 8*384*384
#define NB   256               // histogram buckets per class (LDS-resident)
#define TPB  192               // 3 waves/block
#define NBLK 1536              // 6 blocks/CU exactly; 1536*192*4 == MPIX
#define HSZ  (NCLS * NB)       // 4864 histogram words

typedef float vfloat4 __attribute__((ext_vector_type(4)));  // native vec for nontemporal builtin

// Kernel A: 4 consecutive pixels per thread, float4 I/O.
// Online softmax (2 passes over classes; pass 2 re-reads from L2) instead of
// letting the compiler invent a 3-pass reload schedule (VGPR was 56 < the 76
// needed for v[19] float4 -> it was already re-loading behind our back).
// Block-local LDS histogram packs cnt|pos in u32 (block covers 768 px < 65536),
// then flushes skip-zero via u64 global atomics (cnt low32, pos high32),
// eliminating the 29.9 MB partial write + 29.9 MB reduce read + one dispatch.
__global__ void __launch_bounds__(TPB) softmax_err_hist(
    const float* __restrict__ logits,
    const int* __restrict__ label,
    float* __restrict__ errs,                       // [C, M]
    unsigned long long* __restrict__ hist64)        // [HSZ] cnt|pos packed
{
    __shared__ unsigned int hist[HSZ];
    const int tid = threadIdx.x;
    const int b = blockIdx.x;

    for (int i = tid; i < HSZ; i += TPB) hist[i] = 0u;
    __syncthreads();

    const int m = (b * TPB + tid) * 4;        // 4 consecutive pixels, same image
    const int n = m / HW;                     // HW % 4 == 0 -> all 4 px same n
    const int base = m + n * (NCLS - 1) * HW; // float4-aligned (m % 4 == 0)

    const int4 lbl = *(const int4*)(label + m);

    // pass 1: online max + rescaled sum of exp (keeps only mx,s live)
    float4 mx = make_float4(-1e30f, -1e30f, -1e30f, -1e30f);
    float4 s  = make_float4(0.f, 0.f, 0.f, 0.f);
#pragma unroll
    for (int c = 0; c < NCLS; ++c) {
        float4 x = *(const float4*)(logits + base + c * HW);
        float4 nm;
        nm.x = fmaxf(mx.x, x.x); nm.y = fmaxf(mx.y, x.y);
        nm.z = fmaxf(mx.z, x.z); nm.w = fmaxf(mx.w, x.w);
        s.x = s.x * __expf(mx.x - nm.x) + __expf(x.x - nm.x);
        s.y = s.y * __expf(mx.y - nm.y) + __expf(x.y - nm.y);
        s.z = s.z * __expf(mx.z - nm.z) + __expf(x.z - nm.z);
        s.w = s.w * __expf(mx.w - nm.w) + __expf(x.w - nm.w);
        mx = nm;
    }
    float4 inv = make_float4(1.f / s.x, 1.f / s.y, 1.f / s.z, 1.f / s.w);

    // pass 2: reload (L2-resident), p -> err -> store + histogram
#pragma unroll
    for (int c = 0; c < NCLS; ++c) {
        float4 x = *(const float4*)(logits + base + c * HW);
        float4 p;
        p.x = __expf(x.x - mx.x) * inv.x;
        p.y = __expf(x.y - mx.y) * inv.y;
        p.z = __expf(x.z - mx.z) * inv.z;
        p.w = __expf(x.w - mx.w) * inv.w;
        float4 err;
        err.x = (c == lbl.x) ? (1.0f - p.x) : p.x;
        err.y = (c == lbl.y) ? (1.0f - p.y) : p.y;
        err.z = (c == lbl.z) ? (1.0f - p.z) : p.z;
        err.w = (c == lbl.w) ? (1.0f - p.w) : p.w;
        // non-temporal: errs are write-once, keep L2 for the logits re-reads
        vfloat4 ev; ev.x = err.x; ev.y = err.y; ev.z = err.z; ev.w = err.w;
        __builtin_nontemporal_store(ev, (vfloat4*)(errs + (size_t)c * MPIX + m));

        int k0 = min(max((int)(err.x * (float)NB), 0), NB - 1);
        int k1 = min(max((int)(err.y * (float)NB), 0), NB - 1);
        int k2 = min(max((int)(err.z * (float)NB), 0), NB - 1);
        int k3 = min(max((int)(err.w * (float)NB), 0), NB - 1);
        atomicAdd(&hist[c * NB + k0], 1u + ((c == lbl.x) ? 65536u : 0u));
        atomicAdd(&hist[c * NB + k1], 1u + ((c == lbl.y) ? 65536u : 0u));
        atomicAdd(&hist[c * NB + k2], 1u + ((c == lbl.z) ? 65536u : 0u));
        atomicAdd(&hist[c * NB + k3], 1u + ((c == lbl.w) ? 65536u : 0u));
    }
    __syncthreads();

    // skip-zero u64 atomic flush: cnt (16b) -> low32, pos (16b) -> high32
    for (int i = tid; i < HSZ; i += TPB) {
        unsigned int w = hist[i];
        if (w) {
            unsigned long long add =
                (unsigned long long)(w & 0xFFFFu) |
                ((unsigned long long)(w >> 16) << 32);
            atomicAdd(&hist64[i], add);
        }
    }
}

__device__ __forceinline__ double jaccval(unsigned int n, unsigned int p, unsigned int npos)
{
    // J = 1 - (npos - p) / (npos + n - p); define 0/0 -> 0
    unsigned int denom = (npos - p) + n;
    if (denom == 0u) return 0.0;
    return 1.0 - (double)(npos - p) / (double)denom;
}

// Kernel B: one block per class; thread t owns bucket t. Suffix + trapezoid.
__global__ void __launch_bounds__(NB) lovasz_scan(
    const unsigned long long* __restrict__ hist64,
    float* __restrict__ out0)
{
    const int c = blockIdx.x;
    const int t = threadIdx.x;

    __shared__ unsigned int cntS[NB], posS[NB];
    unsigned long long w = hist64[c * NB + t];
    cntS[t] = (unsigned int)(w & 0xFFFFFFFFull);
    posS[t] = (unsigned int)(w >> 32);
    __syncthreads();

    // suffix-exclusive counts (buckets above t) + total positives
    unsigned int N = 0, P = 0, totP = 0;
    for (int u = 0; u < NB; ++u) {
        totP += posS[u];
        if (u > t) { N += cntS[u]; P += posS[u]; }
    }

    double Jprev = jaccval(N, P, totP);
    N += cntS[t]; P += posS[t];
    double Jnew = jaccval(N, P, totP);
    double acc = 0.5 * (Jprev + Jnew);

    __shared__ double red[NB];
    red[t] = acc;
    __syncthreads();
    for (int s2 = NB / 2; s2 > 0; s2 >>= 1) {
        if (t < s2) red[t] += red[t + s2];
        __syncthreads();
    }
    if (t == 0) {
        double loss_c = red[0] / (double)NB;   // × bucket width
        atomicAdd(out0, (float)(loss_c / (double)NCLS));
    }
}

extern "C" void kernel_launch(void* const* d_in, const int* in_sizes, int n_in,
                              void* d_out, int out_size, void* d_ws, size_t ws_size,
                              hipStream_t stream)
{
    const float* logits = (const float*)d_in[0];
    const int*   label  = (const int*)d_in[1];
    float* out = (float*)d_out;

    // ws layout: [hist64 HSZ u64]
    unsigned long long* hist64 = (unsigned long long*)d_ws;

    hipMemsetAsync(d_ws, 0, (size_t)HSZ * sizeof(unsigned long long), stream);
    hipMemsetAsync(d_out, 0, sizeof(float), stream);

    softmax_err_hist<<<NBLK, TPB, 0, stream>>>(logits, label, out + 1, hist64);
    lovasz_scan<<<NCLS, NB, 0, stream>>>(hist64, out);
}

// Round 4
// 216.482 us; speedup vs baseline: 1.0624x; 1.0624x over previous
//
#include <hip/hip_runtime.h>

// Problem constants (N,C,H,W) = (8,19,384,384)
#define NCLS 19
#define HW   147456            // 384*384
#define MPIX 1179648           // 8*384*384
#define NB   256               // histogram buckets per class (LDS-resident)
#define TPB  192               // 3 waves/block
#define NBLK 1536              // 6 blocks/CU exactly; 1536*192*4 == MPIX
#define HSZ  (NCLS * NB)       // 4864 histogram words

// Kernel A: 4 consecutive pixels per thread, float4 I/O.
// All 19 float4 logits held in REGISTERS (launch_bounds(192,4) allows 128
// VGPR; ~112 needed). Round-1's compiler-chosen 3-pass reload (VGPR=56) cost
// 180 MB of cache re-reads; round-3's online softmax cost 3x exp. This does
// one load, one exp, one mul per element. Loads are issued before the LDS
// histogram init so HBM latency hides under it.
// hist[c][k] packs cnt in low 16, pos in high 16 (block covers 768 px < 65536).
// Flush skip-zero via u64 global atomics (cnt low32, pos high32): no partial
// array, no reduce dispatch.
__global__ void __launch_bounds__(TPB, 4) softmax_err_hist(
    const float* __restrict__ logits,
    const int* __restrict__ label,
    float* __restrict__ errs,                       // [C, M]
    unsigned long long* __restrict__ hist64)        // [HSZ] cnt|pos packed
{
    __shared__ unsigned int hist[HSZ];
    const int tid = threadIdx.x;
    const int b = blockIdx.x;

    const int m = (b * TPB + tid) * 4;        // 4 consecutive pixels, same image
    const int n = m / HW;                     // HW % 4 == 0 -> all 4 px same n
    const int base = m + n * (NCLS - 1) * HW; // float4-aligned (m % 4 == 0)

    // issue all loads first; latency overlaps the LDS init below
    const int4 lbl = *(const int4*)(label + m);
    float4 v[NCLS];
#pragma unroll
    for (int c = 0; c < NCLS; ++c)
        v[c] = *(const float4*)(logits + base + c * HW);

    for (int i = tid; i < HSZ; i += TPB) hist[i] = 0u;
    __syncthreads();

    float4 mx = make_float4(-1e30f, -1e30f, -1e30f, -1e30f);
#pragma unroll
    for (int c = 0; c < NCLS; ++c) {
        mx.x = fmaxf(mx.x, v[c].x); mx.y = fmaxf(mx.y, v[c].y);
        mx.z = fmaxf(mx.z, v[c].z); mx.w = fmaxf(mx.w, v[c].w);
    }
    float4 s = make_float4(0.f, 0.f, 0.f, 0.f);
#pragma unroll
    for (int c = 0; c < NCLS; ++c) {
        float4 e;
        e.x = __expf(v[c].x - mx.x); e.y = __expf(v[c].y - mx.y);
        e.z = __expf(v[c].z - mx.z); e.w = __expf(v[c].w - mx.w);
        v[c] = e;
        s.x += e.x; s.y += e.y; s.z += e.z; s.w += e.w;
    }
    float4 inv = make_float4(1.f / s.x, 1.f / s.y, 1.f / s.z, 1.f / s.w);

#pragma unroll
    for (int c = 0; c < NCLS; ++c) {
        float4 p;
        p.x = v[c].x * inv.x; p.y = v[c].y * inv.y;
        p.z = v[c].z * inv.z; p.w = v[c].w * inv.w;
        float4 err;
        err.x = (c == lbl.x) ? (1.0f - p.x) : p.x;
        err.y = (c == lbl.y) ? (1.0f - p.y) : p.y;
        err.z = (c == lbl.z) ? (1.0f - p.z) : p.z;
        err.w = (c == lbl.w) ? (1.0f - p.w) : p.w;
        *(float4*)(errs + (size_t)c * MPIX + m) = err;

        int k0 = min(max((int)(err.x * (float)NB), 0), NB - 1);
        int k1 = min(max((int)(err.y * (float)NB), 0), NB - 1);
        int k2 = min(max((int)(err.z * (float)NB), 0), NB - 1);
        int k3 = min(max((int)(err.w * (float)NB), 0), NB - 1);
        atomicAdd(&hist[c * NB + k0], 1u + ((c == lbl.x) ? 65536u : 0u));
        atomicAdd(&hist[c * NB + k1], 1u + ((c == lbl.y) ? 65536u : 0u));
        atomicAdd(&hist[c * NB + k2], 1u + ((c == lbl.z) ? 65536u : 0u));
        atomicAdd(&hist[c * NB + k3], 1u + ((c == lbl.w) ? 65536u : 0u));
    }
    __syncthreads();

    // skip-zero u64 atomic flush: cnt (16b) -> low32, pos (16b) -> high32
    for (int i = tid; i < HSZ; i += TPB) {
        unsigned int w = hist[i];
        if (w) {
            unsigned long long add =
                (unsigned long long)(w & 0xFFFFu) |
                ((unsigned long long)(w >> 16) << 32);
            atomicAdd(&hist64[i], add);
        }
    }
}

__device__ __forceinline__ double jaccval(unsigned int n, unsigned int p, unsigned int npos)
{
    // J = 1 - (npos - p) / (npos + n - p); define 0/0 -> 0
    unsigned int denom = (npos - p) + n;
    if (denom == 0u) return 0.0;
    return 1.0 - (double)(npos - p) / (double)denom;
}

// Kernel B: one block per class; thread t owns bucket t. Suffix + trapezoid.
__global__ void __launch_bounds__(NB) lovasz_scan(
    const unsigned long long* __restrict__ hist64,
    float* __restrict__ out0)
{
    const int c = blockIdx.x;
    const int t = threadIdx.x;

    __shared__ unsigned int cntS[NB], posS[NB];
    unsigned long long w = hist64[c * NB + t];
    cntS[t] = (unsigned int)(w & 0xFFFFFFFFull);
    posS[t] = (unsigned int)(w >> 32);
    __syncthreads();

    // suffix-exclusive counts (buckets above t) + total positives
    unsigned int N = 0, P = 0, totP = 0;
    for (int u = 0; u < NB; ++u) {
        totP += posS[u];
        if (u > t) { N += cntS[u]; P += posS[u]; }
    }

    double Jprev = jaccval(N, P, totP);
    N += cntS[t]; P += posS[t];
    double Jnew = jaccval(N, P, totP);
    double acc = 0.5 * (Jprev + Jnew);

    __shared__ double red[NB];
    red[t] = acc;
    __syncthreads();
    for (int s2 = NB / 2; s2 > 0; s2 >>= 1) {
        if (t < s2) red[t] += red[t + s2];
        __syncthreads();
    }
    if (t == 0) {
        double loss_c = red[0] / (double)NB;   // × bucket width
        atomicAdd(out0, (float)(loss_c / (double)NCLS));
    }
}

extern "C" void kernel_launch(void* const* d_in, const int* in_sizes, int n_in,
                              void* d_out, int out_size, void* d_ws, size_t ws_size,
                              hipStream_t stream)
{
    const float* logits = (const float*)d_in[0];
    const int*   label  = (const int*)d_in[1];
    float* out = (float*)d_out;

    // ws layout: [hist64 HSZ u64]
    unsigned long long* hist64 = (unsigned long long*)d_ws;

    hipMemsetAsync(d_ws, 0, (size_t)HSZ * sizeof(unsigned long long), stream);
    hipMemsetAsync(d_out, 0, sizeof(float), stream);

    softmax_err_hist<<<NBLK, TPB, 0, stream>>>(logits, label, out + 1, hist64);
    lovasz_scan<<<NCLS, NB, 0, stream>>>(hist64, out);
}